// Round 19
// baseline (238.518 us; speedup 1.0000x reference)
//
#include <hip/hip_runtime.h>
#include <stdint.h>

#define D_DIM 256
#define K_CODES 8192
#define BM 1024                  // rows per block (8 waves x 128 rows)
#define KSPLIT 16                // blockIdx&15 -> codebook slice
#define KSHIFT 4
#define CPB (K_CODES / KSPLIT)   // 512 codes per block, staged ONCE (64 KB fp4)

typedef float f32x4 __attribute__((ext_vector_type(4)));
typedef int i32x4 __attribute__((ext_vector_type(4)));
typedef int i32x8 __attribute__((ext_vector_type(8)));
typedef __attribute__((address_space(3))) uint32_t lds_u32_t;
typedef __attribute__((address_space(1))) uint32_t glb_u32_t;

#define SCALE1 0x7F7F7F7F  // e8m0 127 = 1.0 in every byte (opsel-proof)

// fp4 e2m1 round-to-nearest encode: values {0,.5,1,1.5,2,3,4,6}
__device__ __forceinline__ uint32_t enc4(float v) {
  const float a = fabsf(v);
  const uint32_t s = (v < 0.f) ? 8u : 0u;
  const uint32_t c = a < 0.25f ? 0u : a < 0.75f ? 1u : a < 1.25f ? 2u
                   : a < 1.75f ? 3u : a < 2.5f  ? 4u : a < 3.5f  ? 5u
                   : a < 5.0f  ? 6u : 7u;
  return s | c;
}

// ---------------------------------------------------------------------------
// prep (fused): [0,2048): codebook -> fp4 swizzled rows (128 B) + cnorm.
//               [2048,3072): x -> fp4 row-major (128 B/row).
//               [3072,...): zero amin (partials need no init: fully written).
// ---------------------------------------------------------------------------
__global__ void vq_prep_fused(const float* __restrict__ cb,
                              const float* __restrict__ x,
                              float* __restrict__ cnorm,
                              char* __restrict__ cbb4,
                              char* __restrict__ xq4,
                              uint4* __restrict__ amin_z) {
  if (blockIdx.x >= 3072) {
    const int o = (blockIdx.x - 3072) * 256 + threadIdx.x;
    amin_z[o] = make_uint4(0u, 0u, 0u, 0u);
    return;
  }
  if (blockIdx.x < 2048) {
    const int lane = threadIdx.x & 63;
    const int code = (blockIdx.x * 256 + threadIdx.x) >> 6;
    const float4 v = *(const float4*)(cb + (size_t)code * D_DIM + lane * 4);
    float ss = v.x * v.x + v.y * v.y + v.z * v.z + v.w * v.w;
#pragma unroll
    for (int m = 32; m >= 1; m >>= 1) ss += __shfl_xor(ss, m, 64);
    if (lane == 0) cnorm[code] = 256.0f * ss - 1024.0f;
    const uint32_t u = enc4(-512.0f * v.x) | (enc4(-512.0f * v.y) << 4) |
                       (enc4(-512.0f * v.z) << 8) | (enc4(-512.0f * v.w) << 12);
    const int off = (2 * lane) ^ ((code & 7) << 4);
    *(ushort*)(cbb4 + (size_t)code * 128 + off) = (ushort)u;
  } else {
    const int o = (blockIdx.x - 2048) * 256 + threadIdx.x;  // 32-float segs
    const float* src = x + (size_t)o * 32;
    uint32_t w[4];
#pragma unroll
    for (int j = 0; j < 4; j++) {
      const float4 f0 = *(const float4*)(src + j * 8);
      const float4 f1 = *(const float4*)(src + j * 8 + 4);
      w[j] = enc4(f0.x) | (enc4(f0.y) << 4) | (enc4(f0.z) << 8) |
             (enc4(f0.w) << 12) | (enc4(f1.x) << 16) | (enc4(f1.y) << 20) |
             (enc4(f1.z) << 24) | (enc4(f1.w) << 28);
    }
    *(uint4*)(xq4 + (size_t)o * 16) = make_uint4(w[0], w[1], w[2], w[3]);
  }
}

// epilogue for one acc: stomp code idx into mantissa, running min (2 inst/score)
#define EPILOG(ACC, RFB)                                                     \
  {                                                                          \
    uint32_t sb;                                                             \
    sb = (__builtin_bit_cast(uint32_t, ACC[0]) & 0xFFFFE000u) | colv;        \
    mv[RFB + 0] = fminf(mv[RFB + 0], __builtin_bit_cast(float, sb));         \
    sb = (__builtin_bit_cast(uint32_t, ACC[1]) & 0xFFFFE000u) | colv;        \
    mv[RFB + 1] = fminf(mv[RFB + 1], __builtin_bit_cast(float, sb));         \
    sb = (__builtin_bit_cast(uint32_t, ACC[2]) & 0xFFFFE000u) | colv;        \
    mv[RFB + 2] = fminf(mv[RFB + 2], __builtin_bit_cast(float, sb));         \
    sb = (__builtin_bit_cast(uint32_t, ACC[3]) & 0xFFFFE000u) | colv;        \
    mv[RFB + 3] = fminf(mv[RFB + 3], __builtin_bit_cast(float, sb));         \
  }

// ---------------------------------------------------------------------------
// main: MX-fp4 distance GEMM + in-mantissa argmin.
// 128 ROWS PER WAVE (a[8][2], mv[32]): occupancy is pinned at ~11 waves/CU
// by the scheduler no matter the config (R9/R11/R12/R17/R18 all flat), so
// raise work per resident wave instead: 2x matrix work amortizes the ~2.3k
// cyc fixed per-wave overhead (A-prologue, staging wait, reduce, tails).
// 8 waves x 128 rows = BM 1024; grid 512; 64 KB slice staged ONCE; one
// barrier; ntiles RUNTIME + unroll 1 (anti-spill pin); NO launch_bounds.
// ---------------------------------------------------------------------------
__global__ void vq_main(
    const char* __restrict__ xq4, const char* __restrict__ cbb4,
    const float* __restrict__ cnorm, uint32_t* __restrict__ amin, int ntiles) {
  __shared__ char lds[CPB * 128 + CPB * 4];  // 64 KB B-slice + 2 KB cnorm
  const int tid = threadIdx.x;
  const int lane = tid & 63;
  const int wid = tid >> 6;
  const int ks = blockIdx.x & (KSPLIT - 1);
  const int mb = blockIdx.x >> KSHIFT;
  const int r0 = mb * BM + wid * 128;

  const char* cbk = cbb4 + (size_t)ks * CPB * 128;

  // stage the slice: 8 x (512 thr x 16 B) + cnorm (512 x 4 B)
#pragma unroll
  for (int i = 0; i < 8; i++)
    __builtin_amdgcn_global_load_lds((glb_u32_t*)(cbk + tid * 16 + i * 8192),
                                     (lds_u32_t*)(lds + tid * 16 + i * 8192),
                                     16, 0, 0);
  __builtin_amdgcn_global_load_lds(
      (glb_u32_t*)((const char*)(cnorm + ks * CPB) + tid * 4),
      (lds_u32_t*)(lds + CPB * 128 + tid * 4), 4, 0, 0);

  // A fragments (fp4): lane holds row (lane&15), k = (lane>>4)*32 + t*128
  // + [0,32) -> 16 B each; stored in low half of an i32x8 (hw reads v[0:3]).
  i32x8 a[8][2];
#pragma unroll
  for (int rf = 0; rf < 8; rf++)
#pragma unroll
    for (int t = 0; t < 2; t++) {
      const char* base = xq4 + (size_t)(r0 + rf * 16 + (lane & 15)) * 128 +
                         (lane >> 4) * 16 + t * 64;
      const i32x4 lo = *(const i32x4*)base;
      a[rf][t] = __builtin_shufflevector(lo, lo, 0, 1, 2, 3, -1, -1, -1, -1);
    }

  float mv[32];
#pragma unroll
  for (int i = 0; i < 32; i++) mv[i] = 0.0f;  // scores are all negative

  uint32_t colv = (uint32_t)(ks * CPB + (lane & 15));
  const int key16 = (lane & 7) << 4;
  const int lanebase = (lane & 15) * 128;
  const int g16 = (lane >> 4) * 16;
  const int badr0 = lanebase + (g16 ^ key16);         // t=0 B-frag
  const int badr1 = lanebase + ((64 + g16) ^ key16);  // t=1 B-frag

  __syncthreads();  // the ONLY barrier: staging drained once, here

#pragma unroll 1
  for (int tile = 0; tile < ntiles; tile++) {
    const char* bt = lds + tile * 8192;          // 64 codes x 128 B per tile
    const char* cnt = lds + CPB * 128 + tile * 256;

    float cnv[4];
#pragma unroll
    for (int s = 0; s < 4; s++)
      cnv[s] = *(const float*)(cnt + s * 64 + (lane & 15) * 4);

#pragma unroll
    for (int s = 0; s < 4; s++) {
      const f32x4 cc = {cnv[s], cnv[s], cnv[s], cnv[s]};
      const i32x4 l0 = *(const i32x4*)(bt + s * 2048 + badr0);
      const i32x4 l1 = *(const i32x4*)(bt + s * 2048 + badr1);
      const i32x8 b0 = __builtin_shufflevector(l0, l0, 0, 1, 2, 3, -1, -1, -1, -1);
      const i32x8 b1 = __builtin_shufflevector(l1, l1, 0, 1, 2, 3, -1, -1, -1, -1);
      f32x4 acc0 = __builtin_amdgcn_mfma_scale_f32_16x16x128_f8f6f4(
          a[0][0], b0, cc, 4, 4, 0, SCALE1, 0, SCALE1);
      f32x4 acc1 = __builtin_amdgcn_mfma_scale_f32_16x16x128_f8f6f4(
          a[1][0], b0, cc, 4, 4, 0, SCALE1, 0, SCALE1);
      f32x4 acc2 = __builtin_amdgcn_mfma_scale_f32_16x16x128_f8f6f4(
          a[2][0], b0, cc, 4, 4, 0, SCALE1, 0, SCALE1);
      f32x4 acc3 = __builtin_amdgcn_mfma_scale_f32_16x16x128_f8f6f4(
          a[3][0], b0, cc, 4, 4, 0, SCALE1, 0, SCALE1);
      f32x4 acc4 = __builtin_amdgcn_mfma_scale_f32_16x16x128_f8f6f4(
          a[4][0], b0, cc, 4, 4, 0, SCALE1, 0, SCALE1);
      f32x4 acc5 = __builtin_amdgcn_mfma_scale_f32_16x16x128_f8f6f4(
          a[5][0], b0, cc, 4, 4, 0, SCALE1, 0, SCALE1);
      f32x4 acc6 = __builtin_amdgcn_mfma_scale_f32_16x16x128_f8f6f4(
          a[6][0], b0, cc, 4, 4, 0, SCALE1, 0, SCALE1);
      f32x4 acc7 = __builtin_amdgcn_mfma_scale_f32_16x16x128_f8f6f4(
          a[7][0], b0, cc, 4, 4, 0, SCALE1, 0, SCALE1);
      acc0 = __builtin_amdgcn_mfma_scale_f32_16x16x128_f8f6f4(
          a[0][1], b1, acc0, 4, 4, 0, SCALE1, 0, SCALE1);
      acc1 = __builtin_amdgcn_mfma_scale_f32_16x16x128_f8f6f4(
          a[1][1], b1, acc1, 4, 4, 0, SCALE1, 0, SCALE1);
      acc2 = __builtin_amdgcn_mfma_scale_f32_16x16x128_f8f6f4(
          a[2][1], b1, acc2, 4, 4, 0, SCALE1, 0, SCALE1);
      acc3 = __builtin_amdgcn_mfma_scale_f32_16x16x128_f8f6f4(
          a[3][1], b1, acc3, 4, 4, 0, SCALE1, 0, SCALE1);
      acc4 = __builtin_amdgcn_mfma_scale_f32_16x16x128_f8f6f4(
          a[4][1], b1, acc4, 4, 4, 0, SCALE1, 0, SCALE1);
      acc5 = __builtin_amdgcn_mfma_scale_f32_16x16x128_f8f6f4(
          a[5][1], b1, acc5, 4, 4, 0, SCALE1, 0, SCALE1);
      acc6 = __builtin_amdgcn_mfma_scale_f32_16x16x128_f8f6f4(
          a[6][1], b1, acc6, 4, 4, 0, SCALE1, 0, SCALE1);
      acc7 = __builtin_amdgcn_mfma_scale_f32_16x16x128_f8f6f4(
          a[7][1], b1, acc7, 4, 4, 0, SCALE1, 0, SCALE1);

      EPILOG(acc0, 0)
      EPILOG(acc1, 4)
      EPILOG(acc2, 8)
      EPILOG(acc3, 12)
      EPILOG(acc4, 16)
      EPILOG(acc5, 20)
      EPILOG(acc6, 24)
      EPILOG(acc7, 28)
      colv += 16;
    }
  }

  // reduce the 16 code-lanes per row; merge globally (neg floats: u32 max)
#pragma unroll
  for (int rf = 0; rf < 8; rf++)
#pragma unroll
    for (int j = 0; j < 4; j++) {
      float m = mv[rf * 4 + j];
#pragma unroll
      for (int d = 1; d < 16; d <<= 1) m = fminf(m, __shfl_xor(m, d, 64));
      if ((lane & 15) == 0) {
        const int row = r0 + rf * 16 + (lane >> 4) * 4 + j;
        atomicMax(&amin[row], __builtin_bit_cast(uint32_t, m));
      }
    }
}

// ---------------------------------------------------------------------------
// gather: 1024 blocks x 32 rows. Per wave: 8 rows, loads batched 4 rows at a
// time (8 outstanding 16B loads -> memory parallelism). Coalesced: lane
// covers floats [lane*4, lane*4+4) of a row. Loss partial: wave shfl-reduce
// -> LDS -> PLAIN STORE to partials[block]. NO atomics, NO fences (R16
// lesson: same-address RMW + threadfence serialized and dominated).
// ---------------------------------------------------------------------------
__global__ void vq_gather(const float* __restrict__ x, const float* __restrict__ cb,
                          const uint32_t* __restrict__ amin,
                          float* __restrict__ out,
                          double* __restrict__ partials) {
  __shared__ double part[4];
  const int lane = threadIdx.x & 63;
  const int wid = threadIdx.x >> 6;
  const int rowbase = blockIdx.x * 32 + wid * 8;
  const uint32_t idxv = amin[rowbase + (lane & 7)] & 8191u;  // 8 rows/wave
  float lsum = 0.f;
#pragma unroll
  for (int h = 0; h < 2; h++) {
    float4 e0, e1, e2, e3, v0, v1, v2, v3;
    {
      const uint32_t i0 = __shfl(idxv, h * 4 + 0, 8);
      const uint32_t i1 = __shfl(idxv, h * 4 + 1, 8);
      const uint32_t i2 = __shfl(idxv, h * 4 + 2, 8);
      const uint32_t i3 = __shfl(idxv, h * 4 + 3, 8);
      e0 = *(const float4*)(cb + (size_t)i0 * D_DIM + lane * 4);
      e1 = *(const float4*)(cb + (size_t)i1 * D_DIM + lane * 4);
      e2 = *(const float4*)(cb + (size_t)i2 * D_DIM + lane * 4);
      e3 = *(const float4*)(cb + (size_t)i3 * D_DIM + lane * 4);
      const float* xb = x + (size_t)(rowbase + h * 4) * D_DIM + lane * 4;
      v0 = *(const float4*)(xb);
      v1 = *(const float4*)(xb + D_DIM);
      v2 = *(const float4*)(xb + 2 * D_DIM);
      v3 = *(const float4*)(xb + 3 * D_DIM);
    }
    float* ob = out + 1 + (size_t)(rowbase + h * 4) * D_DIM + lane * 4;
    ob[0] = e0.x; ob[1] = e0.y; ob[2] = e0.z; ob[3] = e0.w;
    ob += D_DIM;
    ob[0] = e1.x; ob[1] = e1.y; ob[2] = e1.z; ob[3] = e1.w;
    ob += D_DIM;
    ob[0] = e2.x; ob[1] = e2.y; ob[2] = e2.z; ob[3] = e2.w;
    ob += D_DIM;
    ob[0] = e3.x; ob[1] = e3.y; ob[2] = e3.z; ob[3] = e3.w;
    lsum += fabsf(e0.x - v0.x) + fabsf(e0.y - v0.y) + fabsf(e0.z - v0.z) +
            fabsf(e0.w - v0.w);
    lsum += fabsf(e1.x - v1.x) + fabsf(e1.y - v1.y) + fabsf(e1.z - v1.z) +
            fabsf(e1.w - v1.w);
    lsum += fabsf(e2.x - v2.x) + fabsf(e2.y - v2.y) + fabsf(e2.z - v2.z) +
            fabsf(e2.w - v2.w);
    lsum += fabsf(e3.x - v3.x) + fabsf(e3.y - v3.y) + fabsf(e3.z - v3.z) +
            fabsf(e3.w - v3.w);
  }
#pragma unroll
  for (int m = 32; m >= 1; m >>= 1) lsum += __shfl_xor(lsum, m, 64);
  if (lane == 0) part[wid] = (double)lsum;
  __syncthreads();
  if (threadIdx.x == 0)
    partials[blockIdx.x] = (part[0] + part[1]) + (part[2] + part[3]);
}

// ---------------------------------------------------------------------------
// fin: fixed-order tree sum of 1024 block partials (deterministic), /N*D.
// ---------------------------------------------------------------------------
__global__ void vq_fin(const double* __restrict__ partials,
                       float* __restrict__ out) {
  __shared__ double s[256];
  const int t = threadIdx.x;
  s[t] = ((partials[t] + partials[t + 256]) +
          (partials[t + 512] + partials[t + 768]));
  __syncthreads();
  for (int st = 128; st > 0; st >>= 1) {
    if (t < st) s[t] += s[t + st];
    __syncthreads();
  }
  if (t == 0) out[0] = (float)(s[0] / 8388608.0);
}

// ---------------------------------------------------------------------------
extern "C" void kernel_launch(void* const* d_in, const int* in_sizes, int n_in,
                              void* d_out, int out_size, void* d_ws, size_t ws_size,
                              hipStream_t stream) {
  const float* x = (const float*)d_in[0];
  const float* cb = (const float*)d_in[1];
  const int N = in_sizes[0] / D_DIM;  // 32768 rows

  char* ws = (char*)d_ws;
  uint32_t* amin = (uint32_t*)ws;                                   // N*4 B
  double* partials = (double*)(ws + (size_t)N * 4);                 // 1024*8 B
  float* cnorm = (float*)(ws + (size_t)N * 4 + 8192);               // K*4 B
  char* cbb4 = ws + (size_t)N * 4 + 8192 + (size_t)K_CODES * 4;     // K*128 B
  char* xq4 = cbb4 + (size_t)K_CODES * 128;                         // N*128 B

  // prep zeroes amin in its tail blocks (partials fully written by gather)
  vq_prep_fused<<<2048 + (N * D_DIM / 32) / 256 + N / 4096, 256, 0, stream>>>(
      cb, x, cnorm, cbb4, xq4, (uint4*)amin);
  vq_main<<<(N / BM) * KSPLIT, 512, 0, stream>>>(xq4, cbb4, cnorm, amin,
                                                 CPB / 64);
  vq_gather<<<N / 32, 256, 0, stream>>>(x, cb, amin, (float*)d_out, partials);
  vq_fin<<<1, 256, 0, stream>>>(partials, (float*)d_out);
}

// Round 20
// 66.014 us; speedup vs baseline: 3.6131x; 3.6131x over previous
//
#include <hip/hip_runtime.h>
#include <stdint.h>

#define D_DIM 256
#define K_CODES 8192
#define BM 1024                  // rows per block (16 waves x 64 rows)
#define KSPLIT 8                 // blockIdx&7 -> codebook slice
#define KSHIFT 3
#define CPB (K_CODES / KSPLIT)   // 1024 codes per block, staged ONCE (128 KB)

typedef float f32x4 __attribute__((ext_vector_type(4)));
typedef int i32x4 __attribute__((ext_vector_type(4)));
typedef int i32x8 __attribute__((ext_vector_type(8)));
typedef __attribute__((address_space(3))) uint32_t lds_u32_t;
typedef __attribute__((address_space(1))) uint32_t glb_u32_t;

#define SCALE1 0x7F7F7F7F  // e8m0 127 = 1.0 in every byte (opsel-proof)

// fp4 e2m1 round-to-nearest encode: values {0,.5,1,1.5,2,3,4,6}
__device__ __forceinline__ uint32_t enc4(float v) {
  const float a = fabsf(v);
  const uint32_t s = (v < 0.f) ? 8u : 0u;
  const uint32_t c = a < 0.25f ? 0u : a < 0.75f ? 1u : a < 1.25f ? 2u
                   : a < 1.75f ? 3u : a < 2.5f  ? 4u : a < 3.5f  ? 5u
                   : a < 5.0f  ? 6u : 7u;
  return s | c;
}

// ---------------------------------------------------------------------------
// prep (fused): [0,2048): codebook -> fp4 swizzled rows (128 B) + cnorm.
//               [2048,3072): x -> fp4 row-major (128 B/row).
//               [3072,...): zero amin (partials need no init: fully written).
// ---------------------------------------------------------------------------
__global__ void vq_prep_fused(const float* __restrict__ cb,
                              const float* __restrict__ x,
                              float* __restrict__ cnorm,
                              char* __restrict__ cbb4,
                              char* __restrict__ xq4,
                              uint4* __restrict__ amin_z) {
  if (blockIdx.x >= 3072) {
    const int o = (blockIdx.x - 3072) * 256 + threadIdx.x;
    amin_z[o] = make_uint4(0u, 0u, 0u, 0u);
    return;
  }
  if (blockIdx.x < 2048) {
    const int lane = threadIdx.x & 63;
    const int code = (blockIdx.x * 256 + threadIdx.x) >> 6;
    const float4 v = *(const float4*)(cb + (size_t)code * D_DIM + lane * 4);
    float ss = v.x * v.x + v.y * v.y + v.z * v.z + v.w * v.w;
#pragma unroll
    for (int m = 32; m >= 1; m >>= 1) ss += __shfl_xor(ss, m, 64);
    if (lane == 0) cnorm[code] = 256.0f * ss - 1024.0f;
    const uint32_t u = enc4(-512.0f * v.x) | (enc4(-512.0f * v.y) << 4) |
                       (enc4(-512.0f * v.z) << 8) | (enc4(-512.0f * v.w) << 12);
    const int off = (2 * lane) ^ ((code & 7) << 4);
    *(ushort*)(cbb4 + (size_t)code * 128 + off) = (ushort)u;
  } else {
    const int o = (blockIdx.x - 2048) * 256 + threadIdx.x;  // 32-float segs
    const float* src = x + (size_t)o * 32;
    uint32_t w[4];
#pragma unroll
    for (int j = 0; j < 4; j++) {
      const float4 f0 = *(const float4*)(src + j * 8);
      const float4 f1 = *(const float4*)(src + j * 8 + 4);
      w[j] = enc4(f0.x) | (enc4(f0.y) << 4) | (enc4(f0.z) << 8) |
             (enc4(f0.w) << 12) | (enc4(f1.x) << 16) | (enc4(f1.y) << 20) |
             (enc4(f1.z) << 24) | (enc4(f1.w) << 28);
    }
    *(uint4*)(xq4 + (size_t)o * 16) = make_uint4(w[0], w[1], w[2], w[3]);
  }
}

// epilogue for one acc: stomp code idx into mantissa, running min (2 inst/score)
#define EPILOG(ACC, RFB)                                                     \
  {                                                                          \
    uint32_t sb;                                                             \
    sb = (__builtin_bit_cast(uint32_t, ACC[0]) & 0xFFFFE000u) | colv;        \
    mv[RFB + 0] = fminf(mv[RFB + 0], __builtin_bit_cast(float, sb));         \
    sb = (__builtin_bit_cast(uint32_t, ACC[1]) & 0xFFFFE000u) | colv;        \
    mv[RFB + 1] = fminf(mv[RFB + 1], __builtin_bit_cast(float, sb));         \
    sb = (__builtin_bit_cast(uint32_t, ACC[2]) & 0xFFFFE000u) | colv;        \
    mv[RFB + 2] = fminf(mv[RFB + 2], __builtin_bit_cast(float, sb));         \
    sb = (__builtin_bit_cast(uint32_t, ACC[3]) & 0xFFFFE000u) | colv;        \
    mv[RFB + 3] = fminf(mv[RFB + 3], __builtin_bit_cast(float, sb));         \
  }

// ---------------------------------------------------------------------------
// main: MX-fp4 distance GEMM + in-mantissa argmin.
// R17 per-wave body UNCHANGED (64 rows/wave, 44 VGPR — R19's 128-row attempt
// spilled at VGPR 64 / 396 MB scratch). Geometry: KSPLIT=8, CPB=1024,
// 16 waves x 1024 thr, grid 256 = EXACTLY 1 block/CU, whole grid resident,
// zero rounds/tail; 64 s-steps per prologue (2x R17's amortization, the
// direction that won at R15). 135 KB LDS < 160 KB.
// ntiles RUNTIME + unroll 1 (anti-spill pin); NO launch_bounds.
// ---------------------------------------------------------------------------
__global__ void vq_main(
    const char* __restrict__ xq4, const char* __restrict__ cbb4,
    const float* __restrict__ cnorm, uint32_t* __restrict__ amin, int ntiles) {
  __shared__ char lds[CPB * 128 + CPB * 4];  // 128 KB B-slice + 4 KB cnorm
  const int tid = threadIdx.x;
  const int lane = tid & 63;
  const int wid = tid >> 6;                  // 0..15
  const int ks = blockIdx.x & (KSPLIT - 1);
  const int mb = blockIdx.x >> KSHIFT;
  const int r0 = mb * BM + wid * 64;

  const char* cbk = cbb4 + (size_t)ks * CPB * 128;

  // stage the slice: 8 x (1024 thr x 16 B) + cnorm (1024 x 4 B)
#pragma unroll
  for (int i = 0; i < 8; i++)
    __builtin_amdgcn_global_load_lds((glb_u32_t*)(cbk + tid * 16 + i * 16384),
                                     (lds_u32_t*)(lds + tid * 16 + i * 16384),
                                     16, 0, 0);
  __builtin_amdgcn_global_load_lds(
      (glb_u32_t*)((const char*)(cnorm + ks * CPB) + tid * 4),
      (lds_u32_t*)(lds + CPB * 128 + tid * 4), 4, 0, 0);

  // A fragments (fp4): lane holds row (lane&15), k = (lane>>4)*32 + t*128
  // + [0,32) -> 16 B each; stored in low half of an i32x8 (hw reads v[0:3]).
  i32x8 a[4][2];
#pragma unroll
  for (int rf = 0; rf < 4; rf++)
#pragma unroll
    for (int t = 0; t < 2; t++) {
      const char* base = xq4 + (size_t)(r0 + rf * 16 + (lane & 15)) * 128 +
                         (lane >> 4) * 16 + t * 64;
      const i32x4 lo = *(const i32x4*)base;
      a[rf][t] = __builtin_shufflevector(lo, lo, 0, 1, 2, 3, -1, -1, -1, -1);
    }

  float mv[16];
#pragma unroll
  for (int i = 0; i < 16; i++) mv[i] = 0.0f;  // scores are all negative

  uint32_t colv = (uint32_t)(ks * CPB + (lane & 15));
  const int key16 = (lane & 7) << 4;
  const int lanebase = (lane & 15) * 128;
  const int g16 = (lane >> 4) * 16;
  const int badr0 = lanebase + (g16 ^ key16);         // t=0 B-frag
  const int badr1 = lanebase + ((64 + g16) ^ key16);  // t=1 B-frag

  __syncthreads();  // the ONLY barrier: staging drained once, here

#pragma unroll 1
  for (int tile = 0; tile < ntiles; tile++) {
    const char* bt = lds + tile * 8192;          // 64 codes x 128 B per tile
    const char* cnt = lds + CPB * 128 + tile * 256;

    float cnv[4];
#pragma unroll
    for (int s = 0; s < 4; s++)
      cnv[s] = *(const float*)(cnt + s * 64 + (lane & 15) * 4);

#pragma unroll
    for (int s = 0; s < 4; s++) {
      const f32x4 cc = {cnv[s], cnv[s], cnv[s], cnv[s]};
      const i32x4 l0 = *(const i32x4*)(bt + s * 2048 + badr0);
      const i32x4 l1 = *(const i32x4*)(bt + s * 2048 + badr1);
      const i32x8 b0 = __builtin_shufflevector(l0, l0, 0, 1, 2, 3, -1, -1, -1, -1);
      const i32x8 b1 = __builtin_shufflevector(l1, l1, 0, 1, 2, 3, -1, -1, -1, -1);
      f32x4 acc0 = __builtin_amdgcn_mfma_scale_f32_16x16x128_f8f6f4(
          a[0][0], b0, cc, 4, 4, 0, SCALE1, 0, SCALE1);
      f32x4 acc1 = __builtin_amdgcn_mfma_scale_f32_16x16x128_f8f6f4(
          a[1][0], b0, cc, 4, 4, 0, SCALE1, 0, SCALE1);
      f32x4 acc2 = __builtin_amdgcn_mfma_scale_f32_16x16x128_f8f6f4(
          a[2][0], b0, cc, 4, 4, 0, SCALE1, 0, SCALE1);
      f32x4 acc3 = __builtin_amdgcn_mfma_scale_f32_16x16x128_f8f6f4(
          a[3][0], b0, cc, 4, 4, 0, SCALE1, 0, SCALE1);
      acc0 = __builtin_amdgcn_mfma_scale_f32_16x16x128_f8f6f4(
          a[0][1], b1, acc0, 4, 4, 0, SCALE1, 0, SCALE1);
      acc1 = __builtin_amdgcn_mfma_scale_f32_16x16x128_f8f6f4(
          a[1][1], b1, acc1, 4, 4, 0, SCALE1, 0, SCALE1);
      acc2 = __builtin_amdgcn_mfma_scale_f32_16x16x128_f8f6f4(
          a[2][1], b1, acc2, 4, 4, 0, SCALE1, 0, SCALE1);
      acc3 = __builtin_amdgcn_mfma_scale_f32_16x16x128_f8f6f4(
          a[3][1], b1, acc3, 4, 4, 0, SCALE1, 0, SCALE1);

      EPILOG(acc0, 0)
      EPILOG(acc1, 4)
      EPILOG(acc2, 8)
      EPILOG(acc3, 12)
      colv += 16;
    }
  }

  // reduce the 16 code-lanes per row; merge globally (neg floats: u32 max)
#pragma unroll
  for (int rf = 0; rf < 4; rf++)
#pragma unroll
    for (int j = 0; j < 4; j++) {
      float m = mv[rf * 4 + j];
#pragma unroll
      for (int d = 1; d < 16; d <<= 1) m = fminf(m, __shfl_xor(m, d, 64));
      if ((lane & 15) == 0) {
        const int row = r0 + rf * 16 + (lane >> 4) * 4 + j;
        atomicMax(&amin[row], __builtin_bit_cast(uint32_t, m));
      }
    }
}

// ---------------------------------------------------------------------------
// gather: 1024 blocks x 32 rows. Per wave: 8 rows, loads batched 4 rows at a
// time (8 outstanding 16B loads -> memory parallelism). Coalesced: lane
// covers floats [lane*4, lane*4+4) of a row. Loss partial: wave shfl-reduce
// -> LDS -> PLAIN STORE to partials[block]. NO atomics, NO fences (R16
// lesson: same-address RMW + threadfence serialized and dominated).
// ---------------------------------------------------------------------------
__global__ void vq_gather(const float* __restrict__ x, const float* __restrict__ cb,
                          const uint32_t* __restrict__ amin,
                          float* __restrict__ out,
                          double* __restrict__ partials) {
  __shared__ double part[4];
  const int lane = threadIdx.x & 63;
  const int wid = threadIdx.x >> 6;
  const int rowbase = blockIdx.x * 32 + wid * 8;
  const uint32_t idxv = amin[rowbase + (lane & 7)] & 8191u;  // 8 rows/wave
  float lsum = 0.f;
#pragma unroll
  for (int h = 0; h < 2; h++) {
    float4 e0, e1, e2, e3, v0, v1, v2, v3;
    {
      const uint32_t i0 = __shfl(idxv, h * 4 + 0, 8);
      const uint32_t i1 = __shfl(idxv, h * 4 + 1, 8);
      const uint32_t i2 = __shfl(idxv, h * 4 + 2, 8);
      const uint32_t i3 = __shfl(idxv, h * 4 + 3, 8);
      e0 = *(const float4*)(cb + (size_t)i0 * D_DIM + lane * 4);
      e1 = *(const float4*)(cb + (size_t)i1 * D_DIM + lane * 4);
      e2 = *(const float4*)(cb + (size_t)i2 * D_DIM + lane * 4);
      e3 = *(const float4*)(cb + (size_t)i3 * D_DIM + lane * 4);
      const float* xb = x + (size_t)(rowbase + h * 4) * D_DIM + lane * 4;
      v0 = *(const float4*)(xb);
      v1 = *(const float4*)(xb + D_DIM);
      v2 = *(const float4*)(xb + 2 * D_DIM);
      v3 = *(const float4*)(xb + 3 * D_DIM);
    }
    float* ob = out + 1 + (size_t)(rowbase + h * 4) * D_DIM + lane * 4;
    ob[0] = e0.x; ob[1] = e0.y; ob[2] = e0.z; ob[3] = e0.w;
    ob += D_DIM;
    ob[0] = e1.x; ob[1] = e1.y; ob[2] = e1.z; ob[3] = e1.w;
    ob += D_DIM;
    ob[0] = e2.x; ob[1] = e2.y; ob[2] = e2.z; ob[3] = e2.w;
    ob += D_DIM;
    ob[0] = e3.x; ob[1] = e3.y; ob[2] = e3.z; ob[3] = e3.w;
    lsum += fabsf(e0.x - v0.x) + fabsf(e0.y - v0.y) + fabsf(e0.z - v0.z) +
            fabsf(e0.w - v0.w);
    lsum += fabsf(e1.x - v1.x) + fabsf(e1.y - v1.y) + fabsf(e1.z - v1.z) +
            fabsf(e1.w - v1.w);
    lsum += fabsf(e2.x - v2.x) + fabsf(e2.y - v2.y) + fabsf(e2.z - v2.z) +
            fabsf(e2.w - v2.w);
    lsum += fabsf(e3.x - v3.x) + fabsf(e3.y - v3.y) + fabsf(e3.z - v3.z) +
            fabsf(e3.w - v3.w);
  }
#pragma unroll
  for (int m = 32; m >= 1; m >>= 1) lsum += __shfl_xor(lsum, m, 64);
  if (lane == 0) part[wid] = (double)lsum;
  __syncthreads();
  if (threadIdx.x == 0)
    partials[blockIdx.x] = (part[0] + part[1]) + (part[2] + part[3]);
}

// ---------------------------------------------------------------------------
// fin: fixed-order tree sum of 1024 block partials (deterministic), /N*D.
// ---------------------------------------------------------------------------
__global__ void vq_fin(const double* __restrict__ partials,
                       float* __restrict__ out) {
  __shared__ double s[256];
  const int t = threadIdx.x;
  s[t] = ((partials[t] + partials[t + 256]) +
          (partials[t + 512] + partials[t + 768]));
  __syncthreads();
  for (int st = 128; st > 0; st >>= 1) {
    if (t < st) s[t] += s[t + st];
    __syncthreads();
  }
  if (t == 0) out[0] = (float)(s[0] / 8388608.0);
}

// ---------------------------------------------------------------------------
extern "C" void kernel_launch(void* const* d_in, const int* in_sizes, int n_in,
                              void* d_out, int out_size, void* d_ws, size_t ws_size,
                              hipStream_t stream) {
  const float* x = (const float*)d_in[0];
  const float* cb = (const float*)d_in[1];
  const int N = in_sizes[0] / D_DIM;  // 32768 rows

  char* ws = (char*)d_ws;
  uint32_t* amin = (uint32_t*)ws;                                   // N*4 B
  double* partials = (double*)(ws + (size_t)N * 4);                 // 1024*8 B
  float* cnorm = (float*)(ws + (size_t)N * 4 + 8192);               // K*4 B
  char* cbb4 = ws + (size_t)N * 4 + 8192 + (size_t)K_CODES * 4;     // K*128 B
  char* xq4 = cbb4 + (size_t)K_CODES * 128;                         // N*128 B

  // prep zeroes amin in its tail blocks (partials fully written by gather)
  vq_prep_fused<<<2048 + (N * D_DIM / 32) / 256 + N / 4096, 256, 0, stream>>>(
      cb, x, cnorm, cbb4, xq4, (uint4*)amin);
  vq_main<<<(N / BM) * KSPLIT, 1024, 0, stream>>>(xq4, cbb4, cnorm, amin,
                                                  CPB / 64);
  vq_gather<<<N / 32, 256, 0, stream>>>(x, cb, amin, (float*)d_out, partials);
  vq_fin<<<1, 256, 0, stream>>>(partials, (float*)d_out);
}

// Round 21
// 65.997 us; speedup vs baseline: 3.6141x; 1.0003x over previous
//
#include <hip/hip_runtime.h>
#include <stdint.h>

#define D_DIM 256
#define K_CODES 8192
#define BM 1024                  // rows per block (16 waves x 64 rows)
#define KSPLIT 8                 // blockIdx&7 -> codebook slice
#define KSHIFT 3
#define CPB (K_CODES / KSPLIT)   // 1024 codes per block, staged ONCE (128 KB)

typedef float f32x4 __attribute__((ext_vector_type(4)));
typedef int i32x4 __attribute__((ext_vector_type(4)));
typedef int i32x8 __attribute__((ext_vector_type(8)));
typedef __attribute__((address_space(3))) uint32_t lds_u32_t;
typedef __attribute__((address_space(1))) uint32_t glb_u32_t;

#define SCALE1 0x7F7F7F7F  // e8m0 127 = 1.0 in every byte (opsel-proof)

// fp4 e2m1 round-to-nearest encode: values {0,.5,1,1.5,2,3,4,6}
__device__ __forceinline__ uint32_t enc4(float v) {
  const float a = fabsf(v);
  const uint32_t s = (v < 0.f) ? 8u : 0u;
  const uint32_t c = a < 0.25f ? 0u : a < 0.75f ? 1u : a < 1.25f ? 2u
                   : a < 1.75f ? 3u : a < 2.5f  ? 4u : a < 3.5f  ? 5u
                   : a < 5.0f  ? 6u : 7u;
  return s | c;
}

// ---------------------------------------------------------------------------
// prep (fused): [0,2048): codebook -> fp4 swizzled rows (128 B) + cnorm.
//               [2048,3072): x -> fp4 row-major (128 B/row).
//               [3072,...): zero amin (partials need no init: fully written).
// ---------------------------------------------------------------------------
__global__ void vq_prep_fused(const float* __restrict__ cb,
                              const float* __restrict__ x,
                              float* __restrict__ cnorm,
                              char* __restrict__ cbb4,
                              char* __restrict__ xq4,
                              uint4* __restrict__ amin_z) {
  if (blockIdx.x >= 3072) {
    const int o = (blockIdx.x - 3072) * 256 + threadIdx.x;
    amin_z[o] = make_uint4(0u, 0u, 0u, 0u);
    return;
  }
  if (blockIdx.x < 2048) {
    const int lane = threadIdx.x & 63;
    const int code = (blockIdx.x * 256 + threadIdx.x) >> 6;
    const float4 v = *(const float4*)(cb + (size_t)code * D_DIM + lane * 4);
    float ss = v.x * v.x + v.y * v.y + v.z * v.z + v.w * v.w;
#pragma unroll
    for (int m = 32; m >= 1; m >>= 1) ss += __shfl_xor(ss, m, 64);
    if (lane == 0) cnorm[code] = 256.0f * ss - 1024.0f;
    const uint32_t u = enc4(-512.0f * v.x) | (enc4(-512.0f * v.y) << 4) |
                       (enc4(-512.0f * v.z) << 8) | (enc4(-512.0f * v.w) << 12);
    const int off = (2 * lane) ^ ((code & 7) << 4);
    *(ushort*)(cbb4 + (size_t)code * 128 + off) = (ushort)u;
  } else {
    const int o = (blockIdx.x - 2048) * 256 + threadIdx.x;  // 32-float segs
    const float* src = x + (size_t)o * 32;
    uint32_t w[4];
#pragma unroll
    for (int j = 0; j < 4; j++) {
      const float4 f0 = *(const float4*)(src + j * 8);
      const float4 f1 = *(const float4*)(src + j * 8 + 4);
      w[j] = enc4(f0.x) | (enc4(f0.y) << 4) | (enc4(f0.z) << 8) |
             (enc4(f0.w) << 12) | (enc4(f1.x) << 16) | (enc4(f1.y) << 20) |
             (enc4(f1.z) << 24) | (enc4(f1.w) << 28);
    }
    *(uint4*)(xq4 + (size_t)o * 16) = make_uint4(w[0], w[1], w[2], w[3]);
  }
}

// paired epilogue: two s-steps' scores for the same 4 rows; min3 fuses the
// two fminf's -> 3 VALU per 2 scores (was 4). colv1 = colv + 16.
#define EPILOG2(PA, QA, RFB)                                                 \
  {                                                                          \
    uint32_t sa, sb;                                                         \
    sa = (__builtin_bit_cast(uint32_t, PA[0]) & 0xFFFFE000u) | colv;         \
    sb = (__builtin_bit_cast(uint32_t, QA[0]) & 0xFFFFE000u) | colv1;        \
    mv[RFB + 0] = fminf(fminf(mv[RFB + 0], __builtin_bit_cast(float, sa)),   \
                        __builtin_bit_cast(float, sb));                      \
    sa = (__builtin_bit_cast(uint32_t, PA[1]) & 0xFFFFE000u) | colv;         \
    sb = (__builtin_bit_cast(uint32_t, QA[1]) & 0xFFFFE000u) | colv1;        \
    mv[RFB + 1] = fminf(fminf(mv[RFB + 1], __builtin_bit_cast(float, sa)),   \
                        __builtin_bit_cast(float, sb));                      \
    sa = (__builtin_bit_cast(uint32_t, PA[2]) & 0xFFFFE000u) | colv;         \
    sb = (__builtin_bit_cast(uint32_t, QA[2]) & 0xFFFFE000u) | colv1;        \
    mv[RFB + 2] = fminf(fminf(mv[RFB + 2], __builtin_bit_cast(float, sa)),   \
                        __builtin_bit_cast(float, sb));                      \
    sa = (__builtin_bit_cast(uint32_t, PA[3]) & 0xFFFFE000u) | colv;         \
    sb = (__builtin_bit_cast(uint32_t, QA[3]) & 0xFFFFE000u) | colv1;        \
    mv[RFB + 3] = fminf(fminf(mv[RFB + 3], __builtin_bit_cast(float, sa)),   \
                        __builtin_bit_cast(float, sb));                      \
  }

// ---------------------------------------------------------------------------
// main: MX-fp4 distance GEMM + in-mantissa argmin.
// R20 geometry (KSPLIT=8, 16 waves x 1024 thr, grid 256 = 1 block/CU, 128 KB
// slice staged ONCE, one barrier, 64 s-steps/prologue). s-loop now runs as
// 2 PAIRS: 16 MFMAs (8 accs live) then a joint min3 epilogue — cuts the
// dominant VALU pipe 25% (VALUBusy > MfmaUtil since R18).
// ntiles RUNTIME + unroll 1 (anti-spill pin); NO launch_bounds.
// ---------------------------------------------------------------------------
__global__ void vq_main(
    const char* __restrict__ xq4, const char* __restrict__ cbb4,
    const float* __restrict__ cnorm, uint32_t* __restrict__ amin, int ntiles) {
  __shared__ char lds[CPB * 128 + CPB * 4];  // 128 KB B-slice + 4 KB cnorm
  const int tid = threadIdx.x;
  const int lane = tid & 63;
  const int wid = tid >> 6;                  // 0..15
  const int ks = blockIdx.x & (KSPLIT - 1);
  const int mb = blockIdx.x >> KSHIFT;
  const int r0 = mb * BM + wid * 64;

  const char* cbk = cbb4 + (size_t)ks * CPB * 128;

  // stage the slice: 8 x (1024 thr x 16 B) + cnorm (1024 x 4 B)
#pragma unroll
  for (int i = 0; i < 8; i++)
    __builtin_amdgcn_global_load_lds((glb_u32_t*)(cbk + tid * 16 + i * 16384),
                                     (lds_u32_t*)(lds + tid * 16 + i * 16384),
                                     16, 0, 0);
  __builtin_amdgcn_global_load_lds(
      (glb_u32_t*)((const char*)(cnorm + ks * CPB) + tid * 4),
      (lds_u32_t*)(lds + CPB * 128 + tid * 4), 4, 0, 0);

  // A fragments (fp4): lane holds row (lane&15), k = (lane>>4)*32 + t*128
  // + [0,32) -> 16 B each; stored in low half of an i32x8 (hw reads v[0:3]).
  i32x8 a[4][2];
#pragma unroll
  for (int rf = 0; rf < 4; rf++)
#pragma unroll
    for (int t = 0; t < 2; t++) {
      const char* base = xq4 + (size_t)(r0 + rf * 16 + (lane & 15)) * 128 +
                         (lane >> 4) * 16 + t * 64;
      const i32x4 lo = *(const i32x4*)base;
      a[rf][t] = __builtin_shufflevector(lo, lo, 0, 1, 2, 3, -1, -1, -1, -1);
    }

  float mv[16];
#pragma unroll
  for (int i = 0; i < 16; i++) mv[i] = 0.0f;  // scores are all negative

  uint32_t colv = (uint32_t)(ks * CPB + (lane & 15));
  const int key16 = (lane & 7) << 4;
  const int lanebase = (lane & 15) * 128;
  const int g16 = (lane >> 4) * 16;
  const int badr0 = lanebase + (g16 ^ key16);         // t=0 B-frag
  const int badr1 = lanebase + ((64 + g16) ^ key16);  // t=1 B-frag

  __syncthreads();  // the ONLY barrier: staging drained once, here

#pragma unroll 1
  for (int tile = 0; tile < ntiles; tile++) {
    const char* bt = lds + tile * 8192;          // 64 codes x 128 B per tile
    const char* cnt = lds + CPB * 128 + tile * 256;

    float cnv[4];
#pragma unroll
    for (int s = 0; s < 4; s++)
      cnv[s] = *(const float*)(cnt + s * 64 + (lane & 15) * 4);

#pragma unroll
    for (int sp = 0; sp < 2; sp++) {
      f32x4 p0, p1, p2, p3, q0, q1, q2, q3;
      {
        const float cn = cnv[sp * 2];
        const f32x4 cc = {cn, cn, cn, cn};
        const i32x4 l0 = *(const i32x4*)(bt + (sp * 2) * 2048 + badr0);
        const i32x4 l1 = *(const i32x4*)(bt + (sp * 2) * 2048 + badr1);
        const i32x8 b0 =
            __builtin_shufflevector(l0, l0, 0, 1, 2, 3, -1, -1, -1, -1);
        const i32x8 b1 =
            __builtin_shufflevector(l1, l1, 0, 1, 2, 3, -1, -1, -1, -1);
        p0 = __builtin_amdgcn_mfma_scale_f32_16x16x128_f8f6f4(
            a[0][0], b0, cc, 4, 4, 0, SCALE1, 0, SCALE1);
        p1 = __builtin_amdgcn_mfma_scale_f32_16x16x128_f8f6f4(
            a[1][0], b0, cc, 4, 4, 0, SCALE1, 0, SCALE1);
        p2 = __builtin_amdgcn_mfma_scale_f32_16x16x128_f8f6f4(
            a[2][0], b0, cc, 4, 4, 0, SCALE1, 0, SCALE1);
        p3 = __builtin_amdgcn_mfma_scale_f32_16x16x128_f8f6f4(
            a[3][0], b0, cc, 4, 4, 0, SCALE1, 0, SCALE1);
        p0 = __builtin_amdgcn_mfma_scale_f32_16x16x128_f8f6f4(
            a[0][1], b1, p0, 4, 4, 0, SCALE1, 0, SCALE1);
        p1 = __builtin_amdgcn_mfma_scale_f32_16x16x128_f8f6f4(
            a[1][1], b1, p1, 4, 4, 0, SCALE1, 0, SCALE1);
        p2 = __builtin_amdgcn_mfma_scale_f32_16x16x128_f8f6f4(
            a[2][1], b1, p2, 4, 4, 0, SCALE1, 0, SCALE1);
        p3 = __builtin_amdgcn_mfma_scale_f32_16x16x128_f8f6f4(
            a[3][1], b1, p3, 4, 4, 0, SCALE1, 0, SCALE1);
      }
      {
        const float cn = cnv[sp * 2 + 1];
        const f32x4 cc = {cn, cn, cn, cn};
        const i32x4 l0 = *(const i32x4*)(bt + (sp * 2 + 1) * 2048 + badr0);
        const i32x4 l1 = *(const i32x4*)(bt + (sp * 2 + 1) * 2048 + badr1);
        const i32x8 b0 =
            __builtin_shufflevector(l0, l0, 0, 1, 2, 3, -1, -1, -1, -1);
        const i32x8 b1 =
            __builtin_shufflevector(l1, l1, 0, 1, 2, 3, -1, -1, -1, -1);
        q0 = __builtin_amdgcn_mfma_scale_f32_16x16x128_f8f6f4(
            a[0][0], b0, cc, 4, 4, 0, SCALE1, 0, SCALE1);
        q1 = __builtin_amdgcn_mfma_scale_f32_16x16x128_f8f6f4(
            a[1][0], b0, cc, 4, 4, 0, SCALE1, 0, SCALE1);
        q2 = __builtin_amdgcn_mfma_scale_f32_16x16x128_f8f6f4(
            a[2][0], b0, cc, 4, 4, 0, SCALE1, 0, SCALE1);
        q3 = __builtin_amdgcn_mfma_scale_f32_16x16x128_f8f6f4(
            a[3][0], b0, cc, 4, 4, 0, SCALE1, 0, SCALE1);
        q0 = __builtin_amdgcn_mfma_scale_f32_16x16x128_f8f6f4(
            a[0][1], b1, q0, 4, 4, 0, SCALE1, 0, SCALE1);
        q1 = __builtin_amdgcn_mfma_scale_f32_16x16x128_f8f6f4(
            a[1][1], b1, q1, 4, 4, 0, SCALE1, 0, SCALE1);
        q2 = __builtin_amdgcn_mfma_scale_f32_16x16x128_f8f6f4(
            a[2][1], b1, q2, 4, 4, 0, SCALE1, 0, SCALE1);
        q3 = __builtin_amdgcn_mfma_scale_f32_16x16x128_f8f6f4(
            a[3][1], b1, q3, 4, 4, 0, SCALE1, 0, SCALE1);
      }
      const uint32_t colv1 = colv + 16;
      EPILOG2(p0, q0, 0)
      EPILOG2(p1, q1, 4)
      EPILOG2(p2, q2, 8)
      EPILOG2(p3, q3, 12)
      colv += 32;
    }
  }

  // reduce the 16 code-lanes per row; merge globally (neg floats: u32 max)
#pragma unroll
  for (int rf = 0; rf < 4; rf++)
#pragma unroll
    for (int j = 0; j < 4; j++) {
      float m = mv[rf * 4 + j];
#pragma unroll
      for (int d = 1; d < 16; d <<= 1) m = fminf(m, __shfl_xor(m, d, 64));
      if ((lane & 15) == 0) {
        const int row = r0 + rf * 16 + (lane >> 4) * 4 + j;
        atomicMax(&amin[row], __builtin_bit_cast(uint32_t, m));
      }
    }
}

// ---------------------------------------------------------------------------
// gather: 1024 blocks x 32 rows. Per wave: 8 rows, loads batched 4 rows at a
// time (8 outstanding 16B loads -> memory parallelism). Coalesced: lane
// covers floats [lane*4, lane*4+4) of a row. Loss partial: wave shfl-reduce
// -> LDS -> PLAIN STORE to partials[block]. NO atomics, NO fences (R16
// lesson: same-address RMW + threadfence serialized and dominated).
// ---------------------------------------------------------------------------
__global__ void vq_gather(const float* __restrict__ x, const float* __restrict__ cb,
                          const uint32_t* __restrict__ amin,
                          float* __restrict__ out,
                          double* __restrict__ partials) {
  __shared__ double part[4];
  const int lane = threadIdx.x & 63;
  const int wid = threadIdx.x >> 6;
  const int rowbase = blockIdx.x * 32 + wid * 8;
  const uint32_t idxv = amin[rowbase + (lane & 7)] & 8191u;  // 8 rows/wave
  float lsum = 0.f;
#pragma unroll
  for (int h = 0; h < 2; h++) {
    float4 e0, e1, e2, e3, v0, v1, v2, v3;
    {
      const uint32_t i0 = __shfl(idxv, h * 4 + 0, 8);
      const uint32_t i1 = __shfl(idxv, h * 4 + 1, 8);
      const uint32_t i2 = __shfl(idxv, h * 4 + 2, 8);
      const uint32_t i3 = __shfl(idxv, h * 4 + 3, 8);
      e0 = *(const float4*)(cb + (size_t)i0 * D_DIM + lane * 4);
      e1 = *(const float4*)(cb + (size_t)i1 * D_DIM + lane * 4);
      e2 = *(const float4*)(cb + (size_t)i2 * D_DIM + lane * 4);
      e3 = *(const float4*)(cb + (size_t)i3 * D_DIM + lane * 4);
      const float* xb = x + (size_t)(rowbase + h * 4) * D_DIM + lane * 4;
      v0 = *(const float4*)(xb);
      v1 = *(const float4*)(xb + D_DIM);
      v2 = *(const float4*)(xb + 2 * D_DIM);
      v3 = *(const float4*)(xb + 3 * D_DIM);
    }
    float* ob = out + 1 + (size_t)(rowbase + h * 4) * D_DIM + lane * 4;
    ob[0] = e0.x; ob[1] = e0.y; ob[2] = e0.z; ob[3] = e0.w;
    ob += D_DIM;
    ob[0] = e1.x; ob[1] = e1.y; ob[2] = e1.z; ob[3] = e1.w;
    ob += D_DIM;
    ob[0] = e2.x; ob[1] = e2.y; ob[2] = e2.z; ob[3] = e2.w;
    ob += D_DIM;
    ob[0] = e3.x; ob[1] = e3.y; ob[2] = e3.z; ob[3] = e3.w;
    lsum += fabsf(e0.x - v0.x) + fabsf(e0.y - v0.y) + fabsf(e0.z - v0.z) +
            fabsf(e0.w - v0.w);
    lsum += fabsf(e1.x - v1.x) + fabsf(e1.y - v1.y) + fabsf(e1.z - v1.z) +
            fabsf(e1.w - v1.w);
    lsum += fabsf(e2.x - v2.x) + fabsf(e2.y - v2.y) + fabsf(e2.z - v2.z) +
            fabsf(e2.w - v2.w);
    lsum += fabsf(e3.x - v3.x) + fabsf(e3.y - v3.y) + fabsf(e3.z - v3.z) +
            fabsf(e3.w - v3.w);
  }
#pragma unroll
  for (int m = 32; m >= 1; m >>= 1) lsum += __shfl_xor(lsum, m, 64);
  if (lane == 0) part[wid] = (double)lsum;
  __syncthreads();
  if (threadIdx.x == 0)
    partials[blockIdx.x] = (part[0] + part[1]) + (part[2] + part[3]);
}

// ---------------------------------------------------------------------------
// fin: fixed-order tree sum of 1024 block partials (deterministic), /N*D.
// ---------------------------------------------------------------------------
__global__ void vq_fin(const double* __restrict__ partials,
                       float* __restrict__ out) {
  __shared__ double s[256];
  const int t = threadIdx.x;
  s[t] = ((partials[t] + partials[t + 256]) +
          (partials[t + 512] + partials[t + 768]));
  __syncthreads();
  for (int st = 128; st > 0; st >>= 1) {
    if (t < st) s[t] += s[t + st];
    __syncthreads();
  }
  if (t == 0) out[0] = (float)(s[0] / 8388608.0);
}

// ---------------------------------------------------------------------------
extern "C" void kernel_launch(void* const* d_in, const int* in_sizes, int n_in,
                              void* d_out, int out_size, void* d_ws, size_t ws_size,
                              hipStream_t stream) {
  const float* x = (const float*)d_in[0];
  const float* cb = (const float*)d_in[1];
  const int N = in_sizes[0] / D_DIM;  // 32768 rows

  char* ws = (char*)d_ws;
  uint32_t* amin = (uint32_t*)ws;                                   // N*4 B
  double* partials = (double*)(ws + (size_t)N * 4);                 // 1024*8 B
  float* cnorm = (float*)(ws + (size_t)N * 4 + 8192);               // K*4 B
  char* cbb4 = ws + (size_t)N * 4 + 8192 + (size_t)K_CODES * 4;     // K*128 B
  char* xq4 = cbb4 + (size_t)K_CODES * 128;                         // N*128 B

  // prep zeroes amin in its tail blocks (partials fully written by gather)
  vq_prep_fused<<<2048 + (N * D_DIM / 32) / 256 + N / 4096, 256, 0, stream>>>(
      cb, x, cnorm, cbb4, xq4, (uint4*)amin);
  vq_main<<<(N / BM) * KSPLIT, 1024, 0, stream>>>(xq4, cbb4, cnorm, amin,
                                                  CPB / 64);
  vq_gather<<<N / 32, 256, 0, stream>>>(x, cb, amin, (float*)d_out, partials);
  vq_fin<<<1, 256, 0, stream>>>(partials, (float*)d_out);
}